// Round 14
// baseline (1220.578 us; speedup 1.0000x reference)
//
#include <hip/hip_runtime.h>
#include <hip/hip_fp16.h>

#define TT 1024
#define BB 256
#define II 128
#define HH 256

typedef _Float16 f16x8 __attribute__((ext_vector_type(8)));
typedef __fp16   fp16x2 __attribute__((ext_vector_type(2)));
typedef float    f32x4 __attribute__((ext_vector_type(4)));

union HU { _Float16 h[2]; unsigned u; };
static __device__ __forceinline__ unsigned pack2f(float a, float b)
{
    HU t; t.h[0] = (_Float16)a; t.h[1] = (_Float16)b; return t.u;
}
union PK { fp16x2 h; unsigned u; };
static __device__ __forceinline__ unsigned pkrtz(float a, float b)
{
    PK t; t.h = __builtin_amdgcn_cvt_pkrtz(a, b); return t.u;
}

// LDS-only barrier (global loads/stores stay in flight across steps).
#define LDS_BARRIER()                                            \
    do {                                                         \
        asm volatile("s_waitcnt lgkmcnt(0)" ::: "memory");       \
        __builtin_amdgcn_s_barrier();                            \
        __builtin_amdgcn_sched_barrier(0);                       \
    } while (0)

__device__ __forceinline__ float fast_tanh(float a)
{
    float e = __builtin_amdgcn_exp2f(a * 2.8853900817779268f);
    return 1.0f - 2.0f * __builtin_amdgcn_rcpf(e + 1.0f);
}

static __device__ __forceinline__ f16x8 cvt8(const float* p)
{
    float4 a = *(const float4*)p;
    float4 b = *(const float4*)(p + 4);
    f16x8 r;
    r[0]=(_Float16)a.x; r[1]=(_Float16)a.y; r[2]=(_Float16)a.z; r[3]=(_Float16)a.w;
    r[4]=(_Float16)b.x; r[5]=(_Float16)b.y; r[6]=(_Float16)b.z; r[7]=(_Float16)b.w;
    return r;
}

// ---------- Pre-GEMM: xw = x @ W^T + (bW + bV), fp32 into seq region ----------
__global__ __launch_bounds__(256, 1)
void xw_gemm(const float* __restrict__ x, const float* __restrict__ W,
             const float* __restrict__ bW, const float* __restrict__ bV,
             float* __restrict__ xw)
{
    __shared__ _Float16 Wl[HH * II];
    const int tid  = threadIdx.x;
    const int l    = tid & 63;
    const int wv   = (__builtin_amdgcn_readfirstlane(tid) >> 6) & 3;
    const int lr   = l & 15;
    const int kgrp = l >> 4;

    {
        const int row = tid;
        const float4* src = (const float4*)(W + (size_t)row * II);
        unsigned* dst = (unsigned*)Wl;
        const int sw = (row & 7) << 4;
#pragma unroll
        for (int q = 0; q < II / 4; ++q) {
            float4 v = src[q];
            dst[(row * 256 + ((q * 8) ^ sw)) >> 2]     = pack2f(v.x, v.y);
            dst[(row * 256 + ((q * 8 + 4) ^ sw)) >> 2] = pack2f(v.z, v.w);
        }
    }
    __syncthreads();

    const size_t Mbase = (size_t)blockIdx.x * 64;
    const size_t arow  = Mbase + 16 * wv + lr;

    f16x8 afr[4];
#pragma unroll
    for (int kc = 0; kc < 4; ++kc)
        afr[kc] = cvt8(x + arow * II + kc * 32 + kgrp * 8);

    f32x4 acc[16];
#pragma unroll
    for (int nt = 0; nt < 16; ++nt) acc[nt] = f32x4{0.f, 0.f, 0.f, 0.f};

#pragma unroll
    for (int nt = 0; nt < 16; ++nt) {
        const int col = nt * 16 + lr;
        const int sw  = (col & 7) << 4;
#pragma unroll
        for (int kc = 0; kc < 4; ++kc) {
            f16x8 bfr = *(const f16x8*)((const char*)Wl + col * 256 +
                                        ((kc * 64 + kgrp * 16) ^ sw));
            acc[nt] = __builtin_amdgcn_mfma_f32_16x16x32_f16(afr[kc], bfr, acc[nt], 0, 0, 0);
        }
    }
#pragma unroll
    for (int nt = 0; nt < 16; ++nt) {
        const float bias = bW[nt * 16 + lr] + bV[nt * 16 + lr];
#pragma unroll
        for (int r = 0; r < 4; ++r) {
            size_t row = Mbase + 16 * wv + kgrp * 4 + r;
            xw[row * HH + nt * 16 + lr] = acc[nt][r] + bias;
        }
    }
}

// ---------- Recurrence with permuted-V: D layout == next B-frag layout ----------
// 16 WGs x 256 thr (4 waves). Wave wv owns col-blocks q=2wv,2wv+1 (64 cols).
// Tile t (t=0..3): pair q=2wv+(t>>1), jhalf=t&1; A rows permuted:
//   sigma(t, m) = 32q + 8*(m>>2) + 4*jhalf + (m&3)   (m = lane&15)
// => D at lane (kg,lr), reg r = col 32q+8kg+4jh+r, batch lr — exactly the
// B-fragment element k=32q+8kg+j (j=r or 4+r) for batch lr. Redistribution
// needs NO shuffles: tanh -> cvt_pkrtz -> one b128 LDS write per q-block.
// LDS layout: h[batch lr][k] f16, row 512B, XOR swizzle ^((lr&7)<<4) on both
// write and read. xw cols per lane are CONTIGUOUS (base..base+3): f32x4
// loads/stores on all 64 lanes. Bias pre-folded into xw by the GEMM.
__global__ __launch_bounds__(256, 1)
void rnn_mfma3(const float* __restrict__ V, float* __restrict__ out)
{
    __shared__ _Float16 hb[2][16 * HH];  // 2 x 8 KB
    const int tid   = threadIdx.x;
    const int l     = tid & 63;
    const int wv    = (__builtin_amdgcn_readfirstlane(tid) >> 6) & 3;
    const int lr    = l & 15;   // batch row (A m-index, B n-index, D col)
    const int kg    = l >> 4;   // k-subgroup
    const int brow0 = blockIdx.x * 16;

    // A-fragments: permuted V rows.
    f16x8 vfr[4][8];
#pragma unroll
    for (int t4 = 0; t4 < 4; ++t4) {
        const int q  = 2 * wv + (t4 >> 1);
        const int jh = t4 & 1;
        const int c  = 32 * q + 8 * (lr >> 2) + 4 * jh + (lr & 3);
#pragma unroll
        for (int kc = 0; kc < 8; ++kc)
            vfr[t4][kc] = cvt8(V + (size_t)c * HH + kc * 32 + kg * 8);
    }

    // Zero both h buffers (h(-1) = 0).
    {
        unsigned* hz = (unsigned*)hb;
#pragma unroll
        for (int q = 0; q < 16; ++q) hz[tid + 256 * q] = 0u;
    }
    __syncthreads();

    // LDS addresses (consistent XOR swizzle).
    int rdaddr[8];
#pragma unroll
    for (int kc = 0; kc < 8; ++kc)
        rdaddr[kc] = lr * 512 + ((kc * 64 + kg * 16) ^ ((lr & 7) << 4));
    int wraddr[2];
#pragma unroll
    for (int qi = 0; qi < 2; ++qi)
        wraddr[qi] = lr * 512 + (((2 * wv + qi) * 64 + kg * 16) ^ ((lr & 7) << 4));

    // Per-tile global col base (contiguous +r).
    int cb[4];
#pragma unroll
    for (int t4 = 0; t4 < 4; ++t4)
        cb[t4] = 32 * (2 * wv + (t4 >> 1)) + 8 * kg + 4 * (t4 & 1);

    float* __restrict__ seq = out;
    float* __restrict__ fin = out + (size_t)TT * BB * HH;

    // xw pipeline: XA holds xw[even t], XB holds xw[odd t].
    f32x4 XA[4], XB[4];
#pragma unroll
    for (int t4 = 0; t4 < 4; ++t4) {
        XA[t4] = *(const f32x4*)(seq + ((size_t)0 * BB + brow0 + lr) * HH + cb[t4]);
        XB[t4] = *(const f32x4*)(seq + ((size_t)1 * BB + brow0 + lr) * HH + cb[t4]);
    }

#define STEP(CUR, NXT, X, T)                                                    \
    {                                                                           \
        const char* hbase = (const char*)&hb[CUR][0];                           \
        f16x8 bfr[8];                                                           \
        _Pragma("unroll")                                                       \
        for (int kc = 0; kc < 8; ++kc)                                          \
            bfr[kc] = *(const f16x8*)(hbase + rdaddr[kc]);                      \
        f32x4 acc[4];                                                           \
        _Pragma("unroll")                                                       \
        for (int t4 = 0; t4 < 4; ++t4) acc[t4] = f32x4{0.f, 0.f, 0.f, 0.f};     \
        _Pragma("unroll")                                                       \
        for (int kc = 0; kc < 8; ++kc) {                                        \
            _Pragma("unroll")                                                   \
            for (int t4 = 0; t4 < 4; ++t4)                                      \
                acc[t4] = __builtin_amdgcn_mfma_f32_16x16x32_f16(               \
                    vfr[t4][kc], bfr[kc], acc[t4], 0, 0, 0);                    \
        }                                                                       \
        f32x4 hv[4];                                                            \
        _Pragma("unroll")                                                       \
        for (int t4 = 0; t4 < 4; ++t4)                                          \
            _Pragma("unroll")                                                   \
            for (int r = 0; r < 4; ++r) hv[t4][r] = acc[t4][r] + X[t4][r];      \
        /* refill X with xw[T+2] (2-step prefetch; clamped reads discarded) */  \
        {                                                                       \
            const int tp = ((T) + 2 < TT) ? (T) + 2 : (TT - 1);                 \
            const float* prow = seq + ((size_t)tp * BB + brow0 + lr) * HH;      \
            _Pragma("unroll")                                                   \
            for (int t4 = 0; t4 < 4; ++t4) X[t4] = *(const f32x4*)(prow + cb[t4]); \
        }                                                                       \
        _Pragma("unroll")                                                       \
        for (int t4 = 0; t4 < 4; ++t4)                                          \
            _Pragma("unroll")                                                   \
            for (int r = 0; r < 4; ++r) hv[t4][r] = fast_tanh(hv[t4][r]);       \
        float* srow = seq + ((size_t)(T) * BB + brow0 + lr) * HH;               \
        _Pragma("unroll")                                                       \
        for (int t4 = 0; t4 < 4; ++t4) *(f32x4*)(srow + cb[t4]) = hv[t4];       \
        if ((T) == TT - 1) {                                                    \
            float* frow = fin + (size_t)(brow0 + lr) * HH;                      \
            _Pragma("unroll")                                                   \
            for (int t4 = 0; t4 < 4; ++t4) *(f32x4*)(frow + cb[t4]) = hv[t4];   \
        }                                                                       \
        char* wbase = (char*)&hb[NXT][0];                                       \
        _Pragma("unroll")                                                       \
        for (int qi = 0; qi < 2; ++qi) {                                        \
            uint4 pk;                                                           \
            pk.x = pkrtz(hv[2 * qi][0],     hv[2 * qi][1]);                     \
            pk.y = pkrtz(hv[2 * qi][2],     hv[2 * qi][3]);                     \
            pk.z = pkrtz(hv[2 * qi + 1][0], hv[2 * qi + 1][1]);                 \
            pk.w = pkrtz(hv[2 * qi + 1][2], hv[2 * qi + 1][3]);                 \
            *(uint4*)(wbase + wraddr[qi]) = pk;                                 \
        }                                                                       \
        LDS_BARRIER();                                                          \
    }

#pragma unroll 1
    for (int t = 0; t < TT; t += 2) {
        STEP(0, 1, XA, t);
        STEP(1, 0, XB, t + 1);
    }
#undef STEP
}

extern "C" void kernel_launch(void* const* d_in, const int* in_sizes, int n_in,
                              void* d_out, int out_size, void* d_ws, size_t ws_size,
                              hipStream_t stream)
{
    const float* x  = (const float*)d_in[0];
    const float* W  = (const float*)d_in[1];
    const float* bW = (const float*)d_in[2];
    const float* V  = (const float*)d_in[3];
    const float* bV = (const float*)d_in[4];
    float* out = (float*)d_out;

    xw_gemm<<<dim3((TT * BB) / 64), dim3(256), 0, stream>>>(x, W, bW, bV, out);
    rnn_mfma3<<<dim3(BB / 16), dim3(256), 0, stream>>>(V, out);
}

// Round 16
// 776.502 us; speedup vs baseline: 1.5719x; 1.5719x over previous
//
#include <hip/hip_runtime.h>
#include <hip/hip_fp16.h>

#define TT 1024
#define BB 256
#define II 128
#define HH 256

typedef _Float16 f16x8 __attribute__((ext_vector_type(8)));
typedef _Float16 h2    __attribute__((ext_vector_type(2)));
typedef float    f32x4 __attribute__((ext_vector_type(4)));

union HU { h2 h; unsigned u; };
static __device__ __forceinline__ h2 as_h2(unsigned v) { HU t; t.u = v; return t.h; }
static __device__ __forceinline__ unsigned pack2f(float a, float b)
{
    HU t; t.h = h2{(_Float16)a, (_Float16)b}; return t.u;
}
static __device__ __forceinline__ float fdot2u(unsigned a, unsigned b, float c)
{
    return __builtin_amdgcn_fdot2(as_h2(a), as_h2(b), c, false);
}

// LDS-only barrier (global loads/stores stay in flight across steps).
#define LDS_BARRIER()                                            \
    do {                                                         \
        asm volatile("s_waitcnt lgkmcnt(0)" ::: "memory");       \
        __builtin_amdgcn_s_barrier();                            \
        __builtin_amdgcn_sched_barrier(0);                       \
    } while (0)

__device__ __forceinline__ float fast_tanh(float a)
{
    float e = __builtin_amdgcn_exp2f(a * 2.8853900817779268f);
    return 1.0f - 2.0f * __builtin_amdgcn_rcpf(e + 1.0f);
}

static __device__ __forceinline__ f16x8 cvt8(const float* p)
{
    float4 a = *(const float4*)p;
    float4 b = *(const float4*)(p + 4);
    f16x8 r;
    r[0]=(_Float16)a.x; r[1]=(_Float16)a.y; r[2]=(_Float16)a.z; r[3]=(_Float16)a.w;
    r[4]=(_Float16)b.x; r[5]=(_Float16)b.y; r[6]=(_Float16)b.z; r[7]=(_Float16)b.w;
    return r;
}

// ---------- Pre-GEMM: xw = x @ W^T + (bW + bV), fp32 into seq region ----------
// Verified passing in R13 (~87 us, HBM-bound).
__global__ __launch_bounds__(256, 1)
void xw_gemm(const float* __restrict__ x, const float* __restrict__ W,
             const float* __restrict__ bW, const float* __restrict__ bV,
             float* __restrict__ xw)
{
    __shared__ _Float16 Wl[HH * II];
    const int tid  = threadIdx.x;
    const int l    = tid & 63;
    const int wv   = (__builtin_amdgcn_readfirstlane(tid) >> 6) & 3;
    const int lr   = l & 15;
    const int kgrp = l >> 4;

    {
        const int row = tid;
        const float4* src = (const float4*)(W + (size_t)row * II);
        unsigned* dst = (unsigned*)Wl;
        const int sw = (row & 7) << 4;
#pragma unroll
        for (int q = 0; q < II / 4; ++q) {
            float4 v = src[q];
            dst[(row * 256 + ((q * 8) ^ sw)) >> 2]     = pack2f(v.x, v.y);
            dst[(row * 256 + ((q * 8 + 4) ^ sw)) >> 2] = pack2f(v.z, v.w);
        }
    }
    __syncthreads();

    const size_t Mbase = (size_t)blockIdx.x * 64;
    const size_t arow  = Mbase + 16 * wv + lr;

    f16x8 afr[4];
#pragma unroll
    for (int kc = 0; kc < 4; ++kc)
        afr[kc] = cvt8(x + arow * II + kc * 32 + kgrp * 8);

    f32x4 acc[16];
#pragma unroll
    for (int nt = 0; nt < 16; ++nt) acc[nt] = f32x4{0.f, 0.f, 0.f, 0.f};

#pragma unroll
    for (int nt = 0; nt < 16; ++nt) {
        const int col = nt * 16 + lr;
        const int sw  = (col & 7) << 4;
#pragma unroll
        for (int kc = 0; kc < 4; ++kc) {
            f16x8 bfr = *(const f16x8*)((const char*)Wl + col * 256 +
                                        ((kc * 64 + kgrp * 16) ^ sw));
            acc[nt] = __builtin_amdgcn_mfma_f32_16x16x32_f16(afr[kc], bfr, acc[nt], 0, 0, 0);
        }
    }
#pragma unroll
    for (int nt = 0; nt < 16; ++nt) {
        const float bias = bW[nt * 16 + lr] + bV[nt * 16 + lr];
#pragma unroll
        for (int r = 0; r < 4; ++r) {
            size_t row = Mbase + 16 * wv + kgrp * 4 + r;
            xw[row * HH + nt * 16 + lr] = acc[nt][r] + bias;
        }
    }
}

// ---------- Recurrence: R8's dot2 engine, X-phase removed ----------
// 256 WGs (one per CU, one batch row) x 512 thr (8 waves, 2/SIMD).
// Wave w owns K-slice [32w, 32w+32); thread owns outputs 4l..4l+3
// (Vreg[4][16] = 64 packed VGPRs). Per step: 16 readlane + 64 dot2 per wave,
// partials through pbuf, finalize (waves 0-3) adds prefetched xw (bias
// pre-folded) and tanh. XA/XB parity registers give a TRUE 2-step xw
// prefetch distance (~2000 cyc > 900 cyc HBM latency); rows t+2 still hold
// untouched xw when read. Two LDS-only barriers per step.
__global__ __launch_bounds__(512, 2)
void rnn_v(const float* __restrict__ V, float* __restrict__ out)
{
    const int b   = blockIdx.x;
    const int tid = threadIdx.x;
    const int l   = tid & 63;
    const int w   = (__builtin_amdgcn_readfirstlane(tid) >> 6) & 7;
    const int lb  = 8 * w;  // lanes holding this wave's h pairs

    __shared__ __align__(16) _Float16 hbuf[2][HH];
    __shared__ __align__(16) float    pbuf[8][HH];

    unsigned Vreg[4][16];  // V[4l+c][32w + 2m, 2m+1]
#pragma unroll
    for (int c = 0; c < 4; ++c) {
        const int j = 4 * l + c;
        const float* vr = V + (size_t)j * HH + 32 * w;
#pragma unroll
        for (int m = 0; m < 16; ++m) Vreg[c][m] = pack2f(vr[2 * m], vr[2 * m + 1]);
    }

    if (tid < HH) { hbuf[0][tid] = (_Float16)0.f; hbuf[1][tid] = (_Float16)0.f; }
    __syncthreads();

    float* __restrict__ seq = out;                         // (T,B,H) fp32
    float* __restrict__ fin = out + (size_t)TT * BB * HH;  // (B,H) fp32

    // Parity xw prefetch registers (bias already folded in by the GEMM).
    float XA = 0.f, XB = 0.f;
    if (tid < HH) {
        XA = seq[((size_t)0 * BB + b) * HH + tid];
        XB = seq[((size_t)1 * BB + b) * HH + tid];
    }

#define RSTEP(P, X, T)                                                          \
    {                                                                           \
        uint2 hv = *(const uint2*)&hbuf[P][4 * l]; /* h[4l..4l+3] */            \
        float va[4][2] = {{0.f,0.f},{0.f,0.f},{0.f,0.f},{0.f,0.f}};             \
        _Pragma("unroll")                                                       \
        for (int i2 = 0; i2 < 8; ++i2) {                                        \
            unsigned s0 = (unsigned)__builtin_amdgcn_readlane((int)hv.x, lb + i2); \
            unsigned s1 = (unsigned)__builtin_amdgcn_readlane((int)hv.y, lb + i2); \
            _Pragma("unroll")                                                   \
            for (int c = 0; c < 4; ++c) {                                       \
                va[c][0] = fdot2u(s0, Vreg[c][2 * i2],     va[c][0]);           \
                va[c][1] = fdot2u(s1, Vreg[c][2 * i2 + 1], va[c][1]);           \
            }                                                                   \
        }                                                                       \
        f32x4 tot;                                                              \
        tot[0] = va[0][0] + va[0][1];                                           \
        tot[1] = va[1][0] + va[1][1];                                           \
        tot[2] = va[2][0] + va[2][1];                                           \
        tot[3] = va[3][0] + va[3][1];                                           \
        *(f32x4*)&pbuf[w][4 * l] = tot;                                         \
        LDS_BARRIER(); /* pbuf visible */                                       \
        if (tid < HH) {                                                         \
            float p0 = pbuf[0][tid], p1 = pbuf[1][tid];                         \
            float p2 = pbuf[2][tid], p3 = pbuf[3][tid];                         \
            float p4 = pbuf[4][tid], p5 = pbuf[5][tid];                         \
            float p6 = pbuf[6][tid], p7 = pbuf[7][tid];                         \
            float r  = (((p0 + p1) + (p2 + p3)) + ((p4 + p5) + (p6 + p7))) + X; \
            float hf = fast_tanh(r);                                            \
            seq[((size_t)(T) * BB + b) * HH + tid] = hf;                        \
            hbuf[(P) ^ 1][tid] = (_Float16)hf;                                  \
            if ((T) == TT - 1) fin[(size_t)b * HH + tid] = hf;                  \
            const int tp = ((T) + 2 < TT) ? (T) + 2 : (TT - 1);                 \
            X = seq[((size_t)tp * BB + b) * HH + tid];                          \
        }                                                                       \
        LDS_BARRIER(); /* h(T) visible */                                       \
    }

#pragma unroll 1
    for (int t = 0; t < TT; t += 2) {
        RSTEP(0, XA, t);
        RSTEP(1, XB, t + 1);
    }
#undef RSTEP
}

extern "C" void kernel_launch(void* const* d_in, const int* in_sizes, int n_in,
                              void* d_out, int out_size, void* d_ws, size_t ws_size,
                              hipStream_t stream)
{
    const float* x  = (const float*)d_in[0];
    const float* W  = (const float*)d_in[1];
    const float* bW = (const float*)d_in[2];
    const float* V  = (const float*)d_in[3];
    const float* bV = (const float*)d_in[4];
    float* out = (float*)d_out;

    xw_gemm<<<dim3((TT * BB) / 64), dim3(256), 0, stream>>>(x, W, bW, bV, out);
    rnn_v<<<dim3(BB), dim3(512), 0, stream>>>(V, out);
}